// Round 5
// baseline (111.850 us; speedup 1.0000x reference)
//
#include <hip/hip_runtime.h>
#include <math.h>

// NetVLAD: B=8, N=2048, D=128, K=64, fp32 in/out.
#define BB 8
#define NN 2048
#define DD 128
#define KK 64
#define PP 128           // blocks per batch for K1 (1024 blocks = 4/CU: measured-best occupancy)
#define NPB (NN / PP)    // 16 descriptors per block, one pass

// ---------------------------------------------------------------------------
// K1 v5: v3 structure (PP=128, 2 barriers — measured best: time scaled
// inverse-linearly with occupancy between v3 and v4) + v4's verified
// epilogue fold (-sumA*c applied here; part_sA eliminated).
//   load:     thread t loads 8 floats of row i0 = t>>4 straight to registers
//             (coalesced dwordx4 x2); centroid frags + ||c||^2 overlap.
//   norm:     4-shfl 16-lane reduce, scale in regs, write xs once.
//   bar 1
//   Phase B:  16 independent dot+exp chains; per-wave softmax partial via
//             3 shfl -> sL[i][wave].
//   bar 2
//   Phase C:  16 unrolled accumulate chains; rs via float4 broadcast of sL.
//   epilogue: acc -= sA * c (e's are pr-replicated so sA is the full block
//             sumA — verified numerically in round 4), write 32 MB partials.
// ---------------------------------------------------------------------------
__global__ __launch_bounds__(256, 4) void netvlad_k1(
    const float* __restrict__ x, const float* __restrict__ cent,
    float* __restrict__ part_acc)
{
    const int b    = blockIdx.x >> 7;    // / PP
    const int p    = blockIdx.x & 127;   // % PP
    const int t    = threadIdx.x;
    const int kq   = t >> 3;             // 0..31: owns k = {2kq, 2kq+1}
    const int pr   = t & 7;              // 0..7: owns d-range [pr*16, +16)
    const int dbase = pr * 16;
    const int wave = t >> 6;

    __shared__ __align__(16) float xs[NPB][DD];  // 8 KB: normalized descriptors
    __shared__ __align__(16) float sL[NPB][4];   // per-wave exp-sum partials

    // Rotated chunk offsets: slot jj -> chunk ((jj+pr)&3) of the 16-float
    // range (2-way bank alias max, free on gfx950).
    int off[4];
    #pragma unroll
    for (int jj = 0; jj < 4; ++jj) off[jj] = dbase + (((jj + pr) & 3) << 2);

    // ---- issue x loads first: row i0 = t>>4, floats [tl*4,+4) & [64+tl*4,+4)
    const int i0 = t >> 4, tl = t & 15;
    const float* xr = x + ((size_t)b * NN + (size_t)p * NPB + i0) * DD;
    float4 v0 = *(const float4*)(xr + tl * 4);
    float4 v1 = *(const float4*)(xr + 64 + tl * 4);

    // ---- centroid fragments + ||c_k||^2 (independent chain, overlaps loads)
    float4 cA[4], cB[4];
    float cn2a = 0.f, cn2b = 0.f;
    #pragma unroll
    for (int jj = 0; jj < 4; ++jj) {
        cA[jj] = *(const float4*)(cent + (2 * kq) * DD + off[jj]);
        cB[jj] = *(const float4*)(cent + (2 * kq + 1) * DD + off[jj]);
        cn2a += cA[jj].x*cA[jj].x + cA[jj].y*cA[jj].y + cA[jj].z*cA[jj].z + cA[jj].w*cA[jj].w;
        cn2b += cB[jj].x*cB[jj].x + cB[jj].y*cB[jj].y + cB[jj].z*cB[jj].z + cB[jj].w*cB[jj].w;
    }
    #pragma unroll
    for (int m = 1; m < 8; m <<= 1) {
        cn2a += __shfl_xor(cn2a, m);
        cn2b += __shfl_xor(cn2b, m);
    }

    // ---- normalize row i0 in registers, write xs once
    {
        float ss = v0.x*v0.x + v0.y*v0.y + v0.z*v0.z + v0.w*v0.w
                 + v1.x*v1.x + v1.y*v1.y + v1.z*v1.z + v1.w*v1.w;
        #pragma unroll
        for (int m = 1; m < 16; m <<= 1) ss += __shfl_xor(ss, m);
        const float rn = 1.0f / fmaxf(sqrtf(ss), 1e-12f);
        v0.x *= rn; v0.y *= rn; v0.z *= rn; v0.w *= rn;
        v1.x *= rn; v1.y *= rn; v1.z *= rn; v1.w *= rn;
        *(float4*)(&xs[i0][tl * 4])      = v0;
        *(float4*)(&xs[i0][64 + tl * 4]) = v1;
    }
    __syncthreads();   // bar 1: normalized tile visible

    // ---- Phase B: dots + exp.  assign ∝ exp(||c||^2 - 2 xn·c)
    float e0[NPB], e1[NPB];
    #pragma unroll
    for (int i = 0; i < NPB; ++i) {
        float S0 = 0.f, S1 = 0.f;
        #pragma unroll
        for (int jj = 0; jj < 4; ++jj) {
            float4 v = *(const float4*)(&xs[i][off[jj]]);
            S0 += v.x*cA[jj].x + v.y*cA[jj].y + v.z*cA[jj].z + v.w*cA[jj].w;
            S1 += v.x*cB[jj].x + v.y*cB[jj].y + v.z*cB[jj].z + v.w*cB[jj].w;
        }
        #pragma unroll
        for (int m = 1; m < 8; m <<= 1) {   // reduce across the 8 d-parts
            S0 += __shfl_xor(S0, m);
            S1 += __shfl_xor(S1, m);
        }
        e0[i] = __expf(cn2a - 2.f * S0);
        e1[i] = __expf(cn2b - 2.f * S1);
        // per-wave softmax partial: sum this wave's 16 k's
        float es = e0[i] + e1[i];
        #pragma unroll
        for (int m = 8; m < 64; m <<= 1) es += __shfl_xor(es, m);
        if ((t & 63) == 0) sL[i][wave] = es;
    }
    __syncthreads();   // bar 2: sL complete

    // ---- Phase C: accumulate assign * xn
    float4 acc0[4], acc1[4];
    #pragma unroll
    for (int jj = 0; jj < 4; ++jj) {
        acc0[jj] = make_float4(0.f, 0.f, 0.f, 0.f);
        acc1[jj] = make_float4(0.f, 0.f, 0.f, 0.f);
    }
    float sA0 = 0.f, sA1 = 0.f;
    #pragma unroll
    for (int i = 0; i < NPB; ++i) {
        const float4 s4 = *(const float4*)(&sL[i][0]);   // broadcast
        const float rs = 1.0f / (s4.x + s4.y + s4.z + s4.w);
        const float a0 = e0[i] * rs, a1 = e1[i] * rs;
        sA0 += a0; sA1 += a1;
        #pragma unroll
        for (int jj = 0; jj < 4; ++jj) {
            float4 v = *(const float4*)(&xs[i][off[jj]]);
            acc0[jj].x += a0*v.x; acc0[jj].y += a0*v.y; acc0[jj].z += a0*v.z; acc0[jj].w += a0*v.w;
            acc1[jj].x += a1*v.x; acc1[jj].y += a1*v.y; acc1[jj].z += a1*v.z; acc1[jj].w += a1*v.w;
        }
    }

    // ---- epilogue: fold -sumA*c (verified in round 4), write partials
    const size_t base = (size_t)(b * PP + p) * KK * DD;
    #pragma unroll
    for (int jj = 0; jj < 4; ++jj) {
        acc0[jj].x -= sA0 * cA[jj].x; acc0[jj].y -= sA0 * cA[jj].y;
        acc0[jj].z -= sA0 * cA[jj].z; acc0[jj].w -= sA0 * cA[jj].w;
        acc1[jj].x -= sA1 * cB[jj].x; acc1[jj].y -= sA1 * cB[jj].y;
        acc1[jj].z -= sA1 * cB[jj].z; acc1[jj].w -= sA1 * cB[jj].w;
        *(float4*)(part_acc + base + (2 * kq) * DD + off[jj])     = acc0[jj];
        *(float4*)(part_acc + base + (2 * kq + 1) * DD + off[jj]) = acc1[jj];
    }
}

// ---------------------------------------------------------------------------
// K2 v5: streaming reduce of 128 partials per (b,k). 512 blocks x 512
// threads; each thread sums 8 p's (independent loads, 8-deep chain) for its
// float4 column; 16x32 float4 LDS reduce; intra-norm + global factor
// (sqrt(K)=8 -> 0.125). vs v3-k2 (32-deep chains, ~1.9 TB/s): 4x shorter
// chains, 2x threads -> should approach HBM BW on the 32 MB read.
// ---------------------------------------------------------------------------
__global__ __launch_bounds__(512) void netvlad_k2(
    const float* __restrict__ part_acc, float* __restrict__ out)
{
    const int b  = blockIdx.x >> 6;
    const int k  = blockIdx.x & 63;
    const int t  = threadIdx.x;
    const int d4 = t & 31;               // float4 column 0..31
    const int ps = t >> 5;               // p-slice 0..15

    float4 acc = make_float4(0.f, 0.f, 0.f, 0.f);
    const float* base = part_acc + ((size_t)(b * PP) * KK + k) * DD + d4 * 4;
    #pragma unroll
    for (int j = 0; j < 8; ++j) {        // p = j*16 + ps
        const float4 v = *(const float4*)(base + (size_t)(j * 16 + ps) * KK * DD);
        acc.x += v.x; acc.y += v.y; acc.z += v.z; acc.w += v.w;
    }

    __shared__ __align__(16) float4 red[16][32];
    red[ps][d4] = acc;
    __syncthreads();

    if (t < 32) {
        float4 v = red[0][t];
        #pragma unroll
        for (int s = 1; s < 16; ++s) {
            v.x += red[s][t].x; v.y += red[s][t].y;
            v.z += red[s][t].z; v.w += red[s][t].w;
        }
        float ss = v.x*v.x + v.y*v.y + v.z*v.z + v.w*v.w;
        #pragma unroll
        for (int m = 1; m < 32; m <<= 1) ss += __shfl_xor(ss, m);
        const float rn = 0.125f / fmaxf(sqrtf(ss), 1e-12f);
        v.x *= rn; v.y *= rn; v.z *= rn; v.w *= rn;
        *(float4*)(out + ((size_t)b * KK + k) * DD + t * 4) = v;
    }
}

extern "C" void kernel_launch(void* const* d_in, const int* in_sizes, int n_in,
                              void* d_out, int out_size, void* d_ws, size_t ws_size,
                              hipStream_t stream) {
    const float* x    = (const float*)d_in[0];   // [8, 2048, 128] fp32
    const float* cent = (const float*)d_in[1];   // [64, 128] fp32
    float* out = (float*)d_out;                  // [8, 8192] fp32

    float* part_acc = (float*)d_ws;              // 8*128*64*128 fp32 = 32 MB

    netvlad_k1<<<dim3(BB * PP), dim3(256), 0, stream>>>(x, cent, part_acc);
    netvlad_k2<<<dim3(BB * KK), dim3(512), 0, stream>>>(part_acc, out);
}